// Round 13
// baseline (132.213 us; speedup 1.0000x reference)
//
#include <hip/hip_runtime.h>

// Fused attention block for MI355X (gfx950).
// x[4096,768] fp32 -> QKV bf16 GEMM -> flash attention (12 heads, D=64) -> proj GEMM -> fp32 out.
// MFMA v_mfma_f32_16x16x32_bf16 verified layouts:
//   A-frag: m=lane&15, k=quad*8+j ; B-frag: n=lane&15, k=quad*8+j ; C/D: row=quad*4+reg, col=lane&15.
// v14: cast3 DELETED — fp32->bf16 conversion fused into GEMM staging:
//   gemm0 stages A=x, B=qkv_w from fp32 (float4 x2 -> v_cvt_pk_bf16_f32 x4 -> ds_write_b128;
//   RNE, bit-identical to the old cast3). gemm1 converts B=proj_w; A=aob stays bf16 gload16.
//   Removes a 33 MB bandwidth pass + one serial dispatch. GEMMs are latency-bound (MFMA ~5-7%
//   util) so the added staging VALU rides idle issue slots; frag ds_reads are issued BEFORE
//   stage() so MFMAs schedule under the fp32 load latency; dbuf keeps writes off the hot path.
// flash_attn = v11 EXACT (wave split + deferred-PV + ones-MFMA lsum, proven 72.9us).
//   K/V-in-registers permanently abandoned (v6 remat, v7/v12 spill).
// Softmax is UN-NORMALIZED (no running max: logits bounded, exp2 arg << 128).
// Q is pre-scaled by 8*log2(e) so p = exp2(s) directly (raw v_exp_f32).

typedef short bf16x8 __attribute__((ext_vector_type(8)));
typedef float f32x4 __attribute__((ext_vector_type(4)));
typedef unsigned short u16;
typedef unsigned int u32;

__device__ __forceinline__ u16 f2bf(float f) {
  u32 u = __float_as_uint(f);
  u = (u + 0x7fffu + ((u >> 16) & 1u)) >> 16;  // RNE
  return (u16)u;
}

// HW packed f32x2 -> bf16x2 (RNE; the standard fptrunc lowering on gfx950): [a low, b high]
__device__ __forceinline__ u32 cvtpk(float a, float b) {
  u32 r;
  asm("v_cvt_pk_bf16_f32 %0, %1, %2" : "=v"(r) : "v"(a), "v"(b));
  return r;
}

__device__ __forceinline__ void gload16(const void* g, void* l) {
  __builtin_amdgcn_global_load_lds(
      (const __attribute__((address_space(1))) unsigned int*)g,
      (__attribute__((address_space(3))) unsigned int*)l, 16, 0, 0);
}

// gfx950 cross-lane half-swaps (both registers updated in place); verified in v2/v10 (passed):
__device__ __forceinline__ void pl32swap(u32& x, u32& y) {
  asm("v_permlane32_swap_b32 %0, %1" : "+v"(x), "+v"(y));
}
__device__ __forceinline__ void pl16swap(u32& x, u32& y) {
  asm("v_permlane16_swap_b32 %0, %1" : "+v"(x), "+v"(y));
}

// ---------------- m97-style GEMM, double-buffered, fused fp32->bf16 staging ----------------
// MODE 0: A = x (fp32), B = qkv_w (fp32); scatter bf16 into q/k/v. TM=128 (grid 18x32).
// MODE 1: A = attn-out (bf16), B = proj_w (fp32); fp32 out[M,N]. TM=64 (grid 6x64, TLP fix).
template <int MODE>
__global__ __launch_bounds__(256, 2) void gemm_bt(
    const void* __restrict__ Ain, const void* __restrict__ Bin,
    const float* __restrict__ bias,
    u16* __restrict__ qb, u16* __restrict__ kbuf, u16* __restrict__ vb,
    float* __restrict__ outp, int K, int N) {
  constexpr int TM = (MODE == 1) ? 64 : 128;  // M tile
  constexpr int MI = TM / 32;                 // M frags per wave (wave strip = TM/2 rows)
  __shared__ __align__(16) u16 As[2][TM * 32];
  __shared__ __align__(16) u16 Bs[2][128 * 32];
  const int tid = threadIdx.x, lane = tid & 63, w = tid >> 6;
  const int wr = w >> 1, wc = w & 1, quad = lane >> 4, l15 = lane & 15;
  const int m0 = blockIdx.y * TM, n0 = blockIdx.x * 128;

  const float* Af32 = (const float*)Ain;  // MODE 0
  const u16*   Abf  = (const u16*)Ain;    // MODE 1
  const float* Bf32 = (const float*)Bin;

  f32x4 acc[MI][4];
#pragma unroll
  for (int i = 0; i < MI; ++i)
#pragma unroll
    for (int j = 0; j < 4; ++j) acc[i][j] = (f32x4){0.f, 0.f, 0.f, 0.f};

  // stage K-step k0 into buffer sb. fp32 operands: load 32B, convert (RNE), one 16B ds_write.
  auto stage = [&](int k0, int sb) {
    if (MODE == 0) {
#pragma unroll
      for (int i = 0; i < 2; ++i) {  // A tile 128x32 fp32: 512 chunks of 8 elems
        int chunk = i * 256 + tid;
        int row = chunk >> 2, kc = chunk & 3;
        const float* s = Af32 + (size_t)(m0 + row) * K + k0 + kc * 8;
        float4 a = *(const float4*)s;
        float4 b2 = *(const float4*)(s + 4);
        uint4 pk = {cvtpk(a.x, a.y), cvtpk(a.z, a.w), cvtpk(b2.x, b2.y), cvtpk(b2.z, b2.w)};
        *(uint4*)((char*)&As[sb][0] + chunk * 16) = pk;
      }
    } else {
      int chunk = tid;               // A tile 64x32 bf16: 256 chunks of 16B
      int row = chunk >> 2, kc = chunk & 3;
      gload16(Abf + (size_t)(m0 + row) * K + k0 + kc * 8, (char*)&As[sb][0] + chunk * 16);
    }
#pragma unroll
    for (int i = 0; i < 2; ++i) {    // B tile 128x32 fp32: 512 chunks of 8 elems
      int chunk = i * 256 + tid;
      int row = chunk >> 2, kc = chunk & 3;
      const float* s = Bf32 + (size_t)(n0 + row) * K + k0 + kc * 8;
      float4 a = *(const float4*)s;
      float4 b2 = *(const float4*)(s + 4);
      uint4 pk = {cvtpk(a.x, a.y), cvtpk(a.z, a.w), cvtpk(b2.x, b2.y), cvtpk(b2.z, b2.w)};
      *(uint4*)((char*)&Bs[sb][0] + chunk * 16) = pk;
    }
  };

  // prologue: stage K-tile 0 into buffer 0
  stage(0, 0);

  int ib = 0;
  for (int k0 = 0; k0 < K; k0 += 32, ib ^= 1) {
    __syncthreads();  // staging of ib landed (vmcnt+lgkm drained); all waves done reading ib^1

    // frag ds_reads FIRST (from ib), so MFMAs below can issue while stage's fp32 loads fly
    bf16x8 af[MI], bfr[4];
#pragma unroll
    for (int mi = 0; mi < MI; ++mi)
      af[mi] = *(const bf16x8*)&As[ib][(wr * (TM / 2) + mi * 16 + l15) * 32 + quad * 8];
#pragma unroll
    for (int ni = 0; ni < 4; ++ni)
      bfr[ni] = *(const bf16x8*)&Bs[ib][(wc * 64 + ni * 16 + l15) * 32 + quad * 8];

    if (k0 + 32 < K) stage(k0 + 32, ib ^ 1);  // overlaps MFMAs; lands at NEXT barrier

#pragma unroll
    for (int mi = 0; mi < MI; ++mi)
#pragma unroll
      for (int ni = 0; ni < 4; ++ni)
        acc[mi][ni] = __builtin_amdgcn_mfma_f32_16x16x32_bf16(af[mi], bfr[ni], acc[mi][ni], 0, 0, 0);
  }

#pragma unroll
  for (int mi = 0; mi < MI; ++mi) {
    int row = m0 + wr * (TM / 2) + mi * 16 + quad * 4;
#pragma unroll
    for (int ni = 0; ni < 4; ++ni) {
      int col = n0 + wc * 64 + ni * 16 + l15;
      float bv = bias[col];
      if (MODE == 0) {
        int t = col / 768;
        int rem = col - t * 768;
        int hh = rem >> 6, d = rem & 63;
        if (t == 2) {  // V: transposed [H][64][4096]; 4 rows pack into one ushort4
          u16* dst = vb + (size_t)hh * 64 * 4096 + (size_t)d * 4096 + row;
          ushort4 pk;
          pk.x = f2bf(acc[mi][ni][0] + bv);
          pk.y = f2bf(acc[mi][ni][1] + bv);
          pk.z = f2bf(acc[mi][ni][2] + bv);
          pk.w = f2bf(acc[mi][ni][3] + bv);
          *(ushort4*)dst = pk;
        } else {
          u16* dst = (t == 0 ? qb : kbuf) + (size_t)hh * 4096 * 64 + d;
          // Q carries sqrt(D)=8 (reference quirk) AND log2(e) so attention does p=exp2(s)
          float sc = (t == 0) ? 11.541560327111707f : 1.f;
#pragma unroll
          for (int r = 0; r < 4; ++r)
            dst[(size_t)(row + r) * 64] = f2bf((acc[mi][ni][r] + bv) * sc);
        }
      } else {
#pragma unroll
        for (int r = 0; r < 4; ++r)
          outp[(size_t)(row + r) * N + col] = acc[mi][ni][r] + bv;
      }
    }
  }
}

// ---------------- flash attention (= v11): wave split + deferred-PV + ones-MFMA lsum ----------------
// 1 block = (64 q-rows, head). 4 waves: wave w = (q-half w>>1 [32 qrows], key-half w&1 [32 keys]).
// Iter t: barrier; stage t+1 (incremented base ptrs); K(t) ds_reads; {PV(t-1) + lsum-MFMA(t-1)}
// under K latency; S(t); V(t)->regs; softmax(t) (exp2 + cvt_pk + permlane -> P regs).
__global__ __launch_bounds__(256, 3) void flash_attn(
    const u16* __restrict__ qb, const u16* __restrict__ kb,
    const u16* __restrict__ vtg, u16* __restrict__ ob) {
  __shared__ __align__(16) u16 Ks[2][64 * 64];   // 8 KB each
  __shared__ __align__(16) u16 Vs[2][64 * 64];

  // XCD swizzle: each XCD (b&7) covers 96 consecutive work items = 1.5 heads -> K/V in its L2
  const int b = blockIdx.x;
  const int g = (b & 7) * 96 + (b >> 3);
  const int h = g >> 6;
  const int q0 = (g & 63) * 64;

  const int tid = threadIdx.x, lane = tid & 63, w = tid >> 6;
  const int quad = lane >> 4, l15 = lane & 15;
  const int qh2 = w >> 1, kh = w & 1;            // wave role: (q-half, key-half)
  const u16* qptr = qb + (size_t)h * 4096 * 64;
  const u16* kptr = kb + (size_t)h * 4096 * 64;
  const u16* vptr = vtg + (size_t)h * 64 * 4096; // [d][key]
  const int sw = l15 & 7;                        // read-side swizzle (row&7 == l15&7 for all reads)
  const int u0 = (quad ^ sw) * 8;                // K d-chunk c=0
  const int u1 = ((quad + 4) ^ sw) * 8;          // K d-chunk c=1
  const int uv = (((kh << 2) + quad) ^ sw) * 8;  // V key-chunk for this wave's key-half

  // staging: 512 chunks of 16B per tile; this thread's 2 chunks per tile
  int c0 = w * 64 + lane, c1 = 256 + w * 64 + lane;
  int r0s = c0 >> 3, j0s = ((c0 & 7) ^ (r0s & 7)) * 8;
  int r1s = c1 >> 3, j1s = ((c1 & 7) ^ (r1s & 7)) * 8;

  // Q B-frags (loop-invariant): n=qrow = q0 + qh2*32 + qt*16 + l15, k=d
  bf16x8 qf[2][2];
#pragma unroll
  for (int qt = 0; qt < 2; ++qt)
#pragma unroll
    for (int c = 0; c < 2; ++c)
      qf[qt][c] = *(const bf16x8*)&qptr[(size_t)(q0 + qh2 * 32 + qt * 16 + l15) * 64 + c * 32 + quad * 8];

  f32x4 oacc[2][4];  // O-partial[qt][dt]: row=quad*4+r (qrow), col=l15 (d); this wave's key-half only
  f32x4 lacc[2];     // lsum[qt]: row=quad*4+r (qrow), all cols identical (ones-MFMA output)
#pragma unroll
  for (int qt = 0; qt < 2; ++qt) {
    lacc[qt] = (f32x4){0.f, 0.f, 0.f, 0.f};
#pragma unroll
    for (int dt = 0; dt < 4; ++dt) oacc[qt][dt] = (f32x4){0.f, 0.f, 0.f, 0.f};
  }
  const f32x4 zero4 = (f32x4){0.f, 0.f, 0.f, 0.f};
  bf16x8 onesf;
#pragma unroll
  for (int i = 0; i < 8; ++i) onesf[i] = (short)0x3F80;  // bf16 1.0

  // pipeline registers: P(t) and V(t) frags carried to iteration t+1
  bf16x8 pfprev[2], vprev[4];

  // prologue: stage tile 0 into buffer 0
  gload16(kptr + (size_t)r0s * 64 + j0s, (char*)&Ks[0][0] + c0 * 16);
  gload16(kptr + (size_t)r1s * 64 + j1s, (char*)&Ks[0][0] + c1 * 16);
  gload16(vptr + (size_t)r0s * 4096 + j0s, (char*)&Vs[0][0] + c0 * 16);
  gload16(vptr + (size_t)r1s * 4096 + j1s, (char*)&Vs[0][0] + c1 * 16);

  // staging source pointers, pre-offset to tile 1; incremented each staged tile
  const u16* ks0 = kptr + (size_t)(64 + r0s) * 64 + j0s;
  const u16* ks1 = kptr + (size_t)(64 + r1s) * 64 + j1s;
  const u16* vs0 = vptr + (size_t)r0s * 4096 + 64 + j0s;
  const u16* vs1 = vptr + (size_t)r1s * 4096 + 64 + j1s;

  auto body = [&](int t, int buf) {
    __syncthreads();  // staging of buf complete; all waves done computing on buf^1
    if (t < 63) {     // stage tile t+1 into buf^1 (drained only at the NEXT barrier)
      gload16(ks0, (char*)&Ks[buf ^ 1][0] + c0 * 16);
      gload16(ks1, (char*)&Ks[buf ^ 1][0] + c1 * 16);
      gload16(vs0, (char*)&Vs[buf ^ 1][0] + c0 * 16);
      gload16(vs1, (char*)&Vs[buf ^ 1][0] + c1 * 16);
      ks0 += 64 * 64; ks1 += 64 * 64; vs0 += 64; vs1 += 64;
    }

    // K A-frags for this wave's 32-key half: m=key = kh*32 + mt*16 + l15 (issue first)
    bf16x8 kf[2][2];
#pragma unroll
    for (int mt = 0; mt < 2; ++mt) {
      const u16* kr = &Ks[buf][((kh << 5) + mt * 16 + l15) * 64];
      kf[mt][0] = *(const bf16x8*)(kr + u0);
      kf[mt][1] = *(const bf16x8*)(kr + u1);
    }

    __builtin_amdgcn_s_setprio(1);
    // PV(t-1) + lsum(t-1): pure-register MFMAs — execute under the K ds_read latency
    if (t > 0) {
#pragma unroll
      for (int qt = 0; qt < 2; ++qt) {
#pragma unroll
        for (int dt = 0; dt < 4; ++dt)
          oacc[qt][dt] = __builtin_amdgcn_mfma_f32_16x16x32_bf16(pfprev[qt], vprev[dt], oacc[qt][dt], 0, 0, 0);
        lacc[qt] = __builtin_amdgcn_mfma_f32_16x16x32_bf16(pfprev[qt], onesf, lacc[qt], 0, 0, 0);
      }
    }

    // S^T tiles: A = K (m=key), B = Q regs (n=qrow); s already in log2 units
    f32x4 st[2][2];  // [mt][qt]
#pragma unroll
    for (int mt = 0; mt < 2; ++mt)
#pragma unroll
      for (int qt = 0; qt < 2; ++qt) {
        f32x4 z = __builtin_amdgcn_mfma_f32_16x16x32_bf16(kf[mt][0], qf[qt][0], zero4, 0, 0, 0);
        st[mt][qt] = __builtin_amdgcn_mfma_f32_16x16x32_bf16(kf[mt][1], qf[qt][1], z, 0, 0, 0);
      }
    __builtin_amdgcn_s_setprio(0);

    // V^T B-frags (this key-half) -> carried regs; LGKM overlaps the exp VALU below
#pragma unroll
    for (int dt = 0; dt < 4; ++dt)
      vprev[dt] = *(const bf16x8*)(&Vs[buf][(dt * 16 + l15) * 64] + uv);

    // max-free softmax + in-register P redistribution (verified quad-block transpose)
#pragma unroll
    for (int qt = 0; qt < 2; ++qt) {
      float p00 = __builtin_amdgcn_exp2f(st[0][qt][0]);
      float p01 = __builtin_amdgcn_exp2f(st[0][qt][1]);
      float p02 = __builtin_amdgcn_exp2f(st[0][qt][2]);
      float p03 = __builtin_amdgcn_exp2f(st[0][qt][3]);
      float p10 = __builtin_amdgcn_exp2f(st[1][qt][0]);
      float p11 = __builtin_amdgcn_exp2f(st[1][qt][1]);
      float p12 = __builtin_amdgcn_exp2f(st[1][qt][2]);
      float p13 = __builtin_amdgcn_exp2f(st[1][qt][3]);
      u32 x0 = cvtpk(p00, p01), x1 = cvtpk(p02, p03);  // mt=0 word pairs
      u32 y0 = cvtpk(p10, p11), y1 = cvtpk(p12, p13);  // mt=1 word pairs
      pl32swap(x0, y0); pl16swap(x0, y0);  // x0 = frag word0, y0 = frag word2
      pl32swap(x1, y1); pl16swap(x1, y1);  // x1 = frag word1, y1 = frag word3
      union { u32 u[4]; bf16x8 v; } pu;
      pu.u[0] = x0; pu.u[1] = x1; pu.u[2] = y0; pu.u[3] = y1;
      pfprev[qt] = pu.v;
    }
  };

  for (int tt = 0; tt < 32; ++tt) {
    body(2 * tt, 0);
    body(2 * tt + 1, 1);
  }

  // drain the pipeline: PV(63) + lsum(63)
#pragma unroll
  for (int qt = 0; qt < 2; ++qt) {
#pragma unroll
    for (int dt = 0; dt < 4; ++dt)
      oacc[qt][dt] = __builtin_amdgcn_mfma_f32_16x16x32_bf16(pfprev[qt], vprev[dt], oacc[qt][dt], 0, 0, 0);
    lacc[qt] = __builtin_amdgcn_mfma_f32_16x16x32_bf16(pfprev[qt], onesf, lacc[qt], 0, 0, 0);
  }

  // ---- epilogue: combine key-half partials via dead K/V LDS (no shuffles needed) ----
  // lacc[qt][r] = sum_p P[qrow = qt*16 + quad*4 + r][all 32 keys of this half] (all lanes agree)
  __syncthreads();  // all waves done reading Ks/Vs; safe to reuse as reduction scratch
  float* ored = (float*)&Ks[0][0];  // 2qh x 2qt x 4dt x 64lane x f32x4 = 16 KB (= both Ks bufs)
  float* lred = (float*)&Vs[0][0];  // 2qh x 2qt x 16 floats
  if (kh == 1) {
#pragma unroll
    for (int qt = 0; qt < 2; ++qt) {
#pragma unroll
      for (int dt = 0; dt < 4; ++dt)
        *(f32x4*)&ored[((((qh2 * 2 + qt) * 4 + dt) * 64) + lane) * 4] = oacc[qt][dt];
      if (l15 == 0) {
#pragma unroll
        for (int r = 0; r < 4; ++r)
          lred[(qh2 * 2 + qt) * 16 + quad * 4 + r] = lacc[qt][r];
      }
    }
  }
  __syncthreads();
  if (kh == 0) {
#pragma unroll
    for (int qt = 0; qt < 2; ++qt) {
      f32x4 linv;
#pragma unroll
      for (int r = 0; r < 4; ++r)
        linv[r] = 1.f / (lacc[qt][r] + lred[(qh2 * 2 + qt) * 16 + quad * 4 + r]);
#pragma unroll
      for (int dt = 0; dt < 4; ++dt) {
        f32x4 oo = *(const f32x4*)&ored[((((qh2 * 2 + qt) * 4 + dt) * 64) + lane) * 4];
        int row = q0 + qh2 * 32 + qt * 16 + quad * 4;
        u16* op = ob + (size_t)row * 768 + h * 64 + dt * 16 + l15;
        op[0]       = f2bf((oacc[qt][dt][0] + oo[0]) * linv[0]);
        op[768]     = f2bf((oacc[qt][dt][1] + oo[1]) * linv[1]);
        op[2 * 768] = f2bf((oacc[qt][dt][2] + oo[2]) * linv[2]);
        op[3 * 768] = f2bf((oacc[qt][dt][3] + oo[3]) * linv[3]);
      }
    }
  }
}

extern "C" void kernel_launch(void* const* d_in, const int* in_sizes, int n_in,
                              void* d_out, int out_size, void* d_ws, size_t ws_size,
                              hipStream_t stream) {
  const float* x      = (const float*)d_in[0];
  const float* qkv_w  = (const float*)d_in[1];
  const float* qkv_b  = (const float*)d_in[2];
  const float* proj_w = (const float*)d_in[3];
  const float* proj_b = (const float*)d_in[4];
  float* out = (float*)d_out;

  const int N = 4096, C = 768, H = 12, D = 64, C3 = 2304;
  char* ws = (char*)d_ws;
  size_t off = 0;
  u16* aob   = (u16*)(ws + off); off += (size_t)N * C * 2;       // 6.29 MB attn output (bf16)
  u16* qbuf  = (u16*)(ws + off); off += (size_t)H * N * D * 2;   // 6.29 MB
  u16* kbuf  = (u16*)(ws + off); off += (size_t)H * N * D * 2;
  u16* vbuf  = (u16*)(ws + off); off += (size_t)H * N * D * 2;   // V^T [H][64][4096]

  dim3 g1(C3 / 128, N / 128);  // 18 x 32
  gemm_bt<0><<<g1, 256, 0, stream>>>((const void*)x, (const void*)qkv_w, qkv_b,
                                     qbuf, kbuf, vbuf, nullptr, C, C3);

  flash_attn<<<768, 256, 0, stream>>>(qbuf, kbuf, vbuf, aob);

  dim3 g3(C / 128, N / 64);    // 6 x 64 = 384 blocks (TM=64 retile)
  gemm_bt<1><<<g3, 256, 0, stream>>>((const void*)aob, (const void*)proj_w, proj_b,
                                     nullptr, nullptr, nullptr, out, C, C);
}

// Round 14
// 117.403 us; speedup vs baseline: 1.1261x; 1.1261x over previous
//
#include <hip/hip_runtime.h>

// Fused attention block for MI355X (gfx950).
// x[4096,768] fp32 -> QKV bf16 GEMM -> flash attention (12 heads, D=64) -> proj GEMM -> fp32 out.
// MFMA v_mfma_f32_16x16x32_bf16 verified layouts:
//   A-frag: m=lane&15, k=quad*8+j ; B-frag: n=lane&15, k=quad*8+j ; C/D: row=quad*4+reg, col=lane&15.
// v15 = v11 EXACT REVERT (best measured config, 117.3us total / flash 72.9us):
//   cast3 (one-shot fp32->bf16 of x/qkv_w/proj_w) + 2-barrier gemms (TM=128 / TM=64) +
//   flash v11 (32q x 32k wave split + deferred-PV pipeline + in-register permlane P +
//   ones-MFMA lsum + setprio).
// Closed avenues (ledger): K/V-in-registers (v6 remat, v7/v12 spill at >=64 asm-bank VGPRs);
//   gemm single-barrier dbuf (v13: null); cast-fusion into staging (v14: -14us — reg-staging
//   loses global_load_lds async + fp32 doubles reused-operand traffic; only fuse casts into
//   single-use streams, pre-cast anything with reuse >= 2).
// Softmax is UN-NORMALIZED (no running max: logits bounded, exp2 arg << 128).
// Q is pre-scaled by 8*log2(e) so p = exp2(s) directly (raw v_exp_f32).

typedef short bf16x8 __attribute__((ext_vector_type(8)));
typedef float f32x4 __attribute__((ext_vector_type(4)));
typedef unsigned short u16;
typedef unsigned int u32;

__device__ __forceinline__ u16 f2bf(float f) {
  u32 u = __float_as_uint(f);
  u = (u + 0x7fffu + ((u >> 16) & 1u)) >> 16;  // RNE
  return (u16)u;
}

// HW packed f32x2 -> bf16x2 (RNE; the standard fptrunc lowering on gfx950): [a low, b high]
__device__ __forceinline__ u32 cvtpk(float a, float b) {
  u32 r;
  asm("v_cvt_pk_bf16_f32 %0, %1, %2" : "=v"(r) : "v"(a), "v"(b));
  return r;
}

__device__ __forceinline__ void gload16(const void* g, void* l) {
  __builtin_amdgcn_global_load_lds(
      (const __attribute__((address_space(1))) unsigned int*)g,
      (__attribute__((address_space(3))) unsigned int*)l, 16, 0, 0);
}

// gfx950 cross-lane half-swaps (both registers updated in place); verified in v2/v10 (passed):
__device__ __forceinline__ void pl32swap(u32& x, u32& y) {
  asm("v_permlane32_swap_b32 %0, %1" : "+v"(x), "+v"(y));
}
__device__ __forceinline__ void pl16swap(u32& x, u32& y) {
  asm("v_permlane16_swap_b32 %0, %1" : "+v"(x), "+v"(y));
}

// ---------------- fused fp32 -> bf16 cast of x, qkv_w, proj_w (one launch) ----------------
__global__ void cast3(const float* __restrict__ a, int na4,
                      const float* __restrict__ b, int nb4,
                      const float* __restrict__ c, int nc4,
                      u16* __restrict__ oa, u16* __restrict__ obp, u16* __restrict__ oc) {
  int i = blockIdx.x * blockDim.x + threadIdx.x;
  const float* src;
  u16* dst;
  int j = i;
  if (i < na4) { src = a; dst = oa; }
  else if (i < na4 + nb4) { src = b; dst = obp; j = i - na4; }
  else if (i < na4 + nb4 + nc4) { src = c; dst = oc; j = i - na4 - nb4; }
  else return;
  float4 v = ((const float4*)src)[j];
  ushort4 o;
  o.x = f2bf(v.x); o.y = f2bf(v.y); o.z = f2bf(v.z); o.w = f2bf(v.w);
  ((ushort4*)dst)[j] = o;
}

// ---------------- m97-style GEMM: C[M,N] = A[M,K] * B[N,K]^T + bias ----------------
// MODE 0: scatter bf16 into q/k/v. q,k: [H][4096][64] (q pre-scaled by 8*log2e); v: [H][64][4096].
//         TM=128 (grid 18x32 = 576 blocks).
// MODE 1: fp32 out[M,N] (final projection, N=768). TM=64 -> grid 6x64 = 384 blocks (TLP fix).
template <int MODE>
__global__ __launch_bounds__(256, 2) void gemm_bt(
    const u16* __restrict__ A, const u16* __restrict__ B,
    const float* __restrict__ bias,
    u16* __restrict__ qb, u16* __restrict__ kbuf, u16* __restrict__ vb,
    float* __restrict__ outp, int K, int N) {
  constexpr int TM = (MODE == 1) ? 64 : 128;  // M tile
  constexpr int MI = TM / 32;                 // M frags per wave (wave strip = TM/2 rows)
  __shared__ __align__(16) u16 As[TM * 32];
  __shared__ __align__(16) u16 Bs[128 * 32];
  const int tid = threadIdx.x, lane = tid & 63, w = tid >> 6;
  const int wr = w >> 1, wc = w & 1, quad = lane >> 4, l15 = lane & 15;
  const int m0 = blockIdx.y * TM, n0 = blockIdx.x * 128;

  f32x4 acc[MI][4];
#pragma unroll
  for (int i = 0; i < MI; ++i)
#pragma unroll
    for (int j = 0; j < 4; ++j) acc[i][j] = (f32x4){0.f, 0.f, 0.f, 0.f};

  for (int k0 = 0; k0 < K; k0 += 32) {
    __syncthreads();
#pragma unroll
    for (int i = 0; i < TM / 64; ++i) {      // A tile: TM*4 chunks of 16B
      int chunk = i * 256 + tid;
      int row = chunk >> 2, kc = chunk & 3;
      gload16(A + (size_t)(m0 + row) * K + k0 + kc * 8, (char*)As + chunk * 16);
    }
#pragma unroll
    for (int i = 0; i < 2; ++i) {            // B tile: 512 chunks of 16B
      int chunk = i * 256 + tid;
      int row = chunk >> 2, kc = chunk & 3;
      gload16(B + (size_t)(n0 + row) * K + k0 + kc * 8, (char*)Bs + chunk * 16);
    }
    __syncthreads();
    bf16x8 af[MI], bfr[4];
#pragma unroll
    for (int mi = 0; mi < MI; ++mi)
      af[mi] = *(const bf16x8*)&As[(wr * (TM / 2) + mi * 16 + l15) * 32 + quad * 8];
#pragma unroll
    for (int ni = 0; ni < 4; ++ni)
      bfr[ni] = *(const bf16x8*)&Bs[(wc * 64 + ni * 16 + l15) * 32 + quad * 8];
#pragma unroll
    for (int mi = 0; mi < MI; ++mi)
#pragma unroll
      for (int ni = 0; ni < 4; ++ni)
        acc[mi][ni] = __builtin_amdgcn_mfma_f32_16x16x32_bf16(af[mi], bfr[ni], acc[mi][ni], 0, 0, 0);
  }

#pragma unroll
  for (int mi = 0; mi < MI; ++mi) {
    int row = m0 + wr * (TM / 2) + mi * 16 + quad * 4;
#pragma unroll
    for (int ni = 0; ni < 4; ++ni) {
      int col = n0 + wc * 64 + ni * 16 + l15;
      float bv = bias[col];
      if (MODE == 0) {
        int t = col / 768;
        int rem = col - t * 768;
        int hh = rem >> 6, d = rem & 63;
        if (t == 2) {  // V: transposed [H][64][4096]; 4 rows pack into one ushort4
          u16* dst = vb + (size_t)hh * 64 * 4096 + (size_t)d * 4096 + row;
          ushort4 pk;
          pk.x = f2bf(acc[mi][ni][0] + bv);
          pk.y = f2bf(acc[mi][ni][1] + bv);
          pk.z = f2bf(acc[mi][ni][2] + bv);
          pk.w = f2bf(acc[mi][ni][3] + bv);
          *(ushort4*)dst = pk;
        } else {
          u16* dst = (t == 0 ? qb : kbuf) + (size_t)hh * 4096 * 64 + d;
          // Q carries sqrt(D)=8 (reference quirk) AND log2(e) so attention does p=exp2(s)
          float sc = (t == 0) ? 11.541560327111707f : 1.f;
#pragma unroll
          for (int r = 0; r < 4; ++r)
            dst[(size_t)(row + r) * 64] = f2bf((acc[mi][ni][r] + bv) * sc);
        }
      } else {
#pragma unroll
        for (int r = 0; r < 4; ++r)
          outp[(size_t)(row + r) * N + col] = acc[mi][ni][r] + bv;
      }
    }
  }
}

// ---------------- flash attention (= v11): wave split + deferred-PV + ones-MFMA lsum ----------------
// 1 block = (64 q-rows, head). 4 waves: wave w = (q-half w>>1 [32 qrows], key-half w&1 [32 keys]).
// Iter t: barrier; stage t+1 (incremented base ptrs); K(t) ds_reads; {PV(t-1) + lsum-MFMA(t-1)}
// under K latency; S(t); V(t)->regs; softmax(t) (exp2 + cvt_pk + permlane -> P regs).
__global__ __launch_bounds__(256, 3) void flash_attn(
    const u16* __restrict__ qb, const u16* __restrict__ kb,
    const u16* __restrict__ vtg, u16* __restrict__ ob) {
  __shared__ __align__(16) u16 Ks[2][64 * 64];   // 8 KB each
  __shared__ __align__(16) u16 Vs[2][64 * 64];

  // XCD swizzle: each XCD (b&7) covers 96 consecutive work items = 1.5 heads -> K/V in its L2
  const int b = blockIdx.x;
  const int g = (b & 7) * 96 + (b >> 3);
  const int h = g >> 6;
  const int q0 = (g & 63) * 64;

  const int tid = threadIdx.x, lane = tid & 63, w = tid >> 6;
  const int quad = lane >> 4, l15 = lane & 15;
  const int qh2 = w >> 1, kh = w & 1;            // wave role: (q-half, key-half)
  const u16* qptr = qb + (size_t)h * 4096 * 64;
  const u16* kptr = kb + (size_t)h * 4096 * 64;
  const u16* vptr = vtg + (size_t)h * 64 * 4096; // [d][key]
  const int sw = l15 & 7;                        // read-side swizzle (row&7 == l15&7 for all reads)
  const int u0 = (quad ^ sw) * 8;                // K d-chunk c=0
  const int u1 = ((quad + 4) ^ sw) * 8;          // K d-chunk c=1
  const int uv = (((kh << 2) + quad) ^ sw) * 8;  // V key-chunk for this wave's key-half

  // staging: 512 chunks of 16B per tile; this thread's 2 chunks per tile
  int c0 = w * 64 + lane, c1 = 256 + w * 64 + lane;
  int r0s = c0 >> 3, j0s = ((c0 & 7) ^ (r0s & 7)) * 8;
  int r1s = c1 >> 3, j1s = ((c1 & 7) ^ (r1s & 7)) * 8;

  // Q B-frags (loop-invariant): n=qrow = q0 + qh2*32 + qt*16 + l15, k=d
  bf16x8 qf[2][2];
#pragma unroll
  for (int qt = 0; qt < 2; ++qt)
#pragma unroll
    for (int c = 0; c < 2; ++c)
      qf[qt][c] = *(const bf16x8*)&qptr[(size_t)(q0 + qh2 * 32 + qt * 16 + l15) * 64 + c * 32 + quad * 8];

  f32x4 oacc[2][4];  // O-partial[qt][dt]: row=quad*4+r (qrow), col=l15 (d); this wave's key-half only
  f32x4 lacc[2];     // lsum[qt]: row=quad*4+r (qrow), all cols identical (ones-MFMA output)
#pragma unroll
  for (int qt = 0; qt < 2; ++qt) {
    lacc[qt] = (f32x4){0.f, 0.f, 0.f, 0.f};
#pragma unroll
    for (int dt = 0; dt < 4; ++dt) oacc[qt][dt] = (f32x4){0.f, 0.f, 0.f, 0.f};
  }
  const f32x4 zero4 = (f32x4){0.f, 0.f, 0.f, 0.f};
  bf16x8 onesf;
#pragma unroll
  for (int i = 0; i < 8; ++i) onesf[i] = (short)0x3F80;  // bf16 1.0

  // pipeline registers: P(t) and V(t) frags carried to iteration t+1
  bf16x8 pfprev[2], vprev[4];

  // prologue: stage tile 0 into buffer 0
  gload16(kptr + (size_t)r0s * 64 + j0s, (char*)&Ks[0][0] + c0 * 16);
  gload16(kptr + (size_t)r1s * 64 + j1s, (char*)&Ks[0][0] + c1 * 16);
  gload16(vptr + (size_t)r0s * 4096 + j0s, (char*)&Vs[0][0] + c0 * 16);
  gload16(vptr + (size_t)r1s * 4096 + j1s, (char*)&Vs[0][0] + c1 * 16);

  // staging source pointers, pre-offset to tile 1; incremented each staged tile
  const u16* ks0 = kptr + (size_t)(64 + r0s) * 64 + j0s;
  const u16* ks1 = kptr + (size_t)(64 + r1s) * 64 + j1s;
  const u16* vs0 = vptr + (size_t)r0s * 4096 + 64 + j0s;
  const u16* vs1 = vptr + (size_t)r1s * 4096 + 64 + j1s;

  auto body = [&](int t, int buf) {
    __syncthreads();  // staging of buf complete; all waves done computing on buf^1
    if (t < 63) {     // stage tile t+1 into buf^1 (drained only at the NEXT barrier)
      gload16(ks0, (char*)&Ks[buf ^ 1][0] + c0 * 16);
      gload16(ks1, (char*)&Ks[buf ^ 1][0] + c1 * 16);
      gload16(vs0, (char*)&Vs[buf ^ 1][0] + c0 * 16);
      gload16(vs1, (char*)&Vs[buf ^ 1][0] + c1 * 16);
      ks0 += 64 * 64; ks1 += 64 * 64; vs0 += 64; vs1 += 64;
    }

    // K A-frags for this wave's 32-key half: m=key = kh*32 + mt*16 + l15 (issue first)
    bf16x8 kf[2][2];
#pragma unroll
    for (int mt = 0; mt < 2; ++mt) {
      const u16* kr = &Ks[buf][((kh << 5) + mt * 16 + l15) * 64];
      kf[mt][0] = *(const bf16x8*)(kr + u0);
      kf[mt][1] = *(const bf16x8*)(kr + u1);
    }

    __builtin_amdgcn_s_setprio(1);
    // PV(t-1) + lsum(t-1): pure-register MFMAs — execute under the K ds_read latency
    if (t > 0) {
#pragma unroll
      for (int qt = 0; qt < 2; ++qt) {
#pragma unroll
        for (int dt = 0; dt < 4; ++dt)
          oacc[qt][dt] = __builtin_amdgcn_mfma_f32_16x16x32_bf16(pfprev[qt], vprev[dt], oacc[qt][dt], 0, 0, 0);
        lacc[qt] = __builtin_amdgcn_mfma_f32_16x16x32_bf16(pfprev[qt], onesf, lacc[qt], 0, 0, 0);
      }
    }

    // S^T tiles: A = K (m=key), B = Q regs (n=qrow); s already in log2 units
    f32x4 st[2][2];  // [mt][qt]
#pragma unroll
    for (int mt = 0; mt < 2; ++mt)
#pragma unroll
      for (int qt = 0; qt < 2; ++qt) {
        f32x4 z = __builtin_amdgcn_mfma_f32_16x16x32_bf16(kf[mt][0], qf[qt][0], zero4, 0, 0, 0);
        st[mt][qt] = __builtin_amdgcn_mfma_f32_16x16x32_bf16(kf[mt][1], qf[qt][1], z, 0, 0, 0);
      }
    __builtin_amdgcn_s_setprio(0);

    // V^T B-frags (this key-half) -> carried regs; LGKM overlaps the exp VALU below
#pragma unroll
    for (int dt = 0; dt < 4; ++dt)
      vprev[dt] = *(const bf16x8*)(&Vs[buf][(dt * 16 + l15) * 64] + uv);

    // max-free softmax + in-register P redistribution (verified quad-block transpose)
#pragma unroll
    for (int qt = 0; qt < 2; ++qt) {
      float p00 = __builtin_amdgcn_exp2f(st[0][qt][0]);
      float p01 = __builtin_amdgcn_exp2f(st[0][qt][1]);
      float p02 = __builtin_amdgcn_exp2f(st[0][qt][2]);
      float p03 = __builtin_amdgcn_exp2f(st[0][qt][3]);
      float p10 = __builtin_amdgcn_exp2f(st[1][qt][0]);
      float p11 = __builtin_amdgcn_exp2f(st[1][qt][1]);
      float p12 = __builtin_amdgcn_exp2f(st[1][qt][2]);
      float p13 = __builtin_amdgcn_exp2f(st[1][qt][3]);
      u32 x0 = cvtpk(p00, p01), x1 = cvtpk(p02, p03);  // mt=0 word pairs
      u32 y0 = cvtpk(p10, p11), y1 = cvtpk(p12, p13);  // mt=1 word pairs
      pl32swap(x0, y0); pl16swap(x0, y0);  // x0 = frag word0, y0 = frag word2
      pl32swap(x1, y1); pl16swap(x1, y1);  // x1 = frag word1, y1 = frag word3
      union { u32 u[4]; bf16x8 v; } pu;
      pu.u[0] = x0; pu.u[1] = x1; pu.u[2] = y0; pu.u[3] = y1;
      pfprev[qt] = pu.v;
    }
  };

  for (int tt = 0; tt < 32; ++tt) {
    body(2 * tt, 0);
    body(2 * tt + 1, 1);
  }

  // drain the pipeline: PV(63) + lsum(63)
#pragma unroll
  for (int qt = 0; qt < 2; ++qt) {
#pragma unroll
    for (int dt = 0; dt < 4; ++dt)
      oacc[qt][dt] = __builtin_amdgcn_mfma_f32_16x16x32_bf16(pfprev[qt], vprev[dt], oacc[qt][dt], 0, 0, 0);
    lacc[qt] = __builtin_amdgcn_mfma_f32_16x16x32_bf16(pfprev[qt], onesf, lacc[qt], 0, 0, 0);
  }

  // ---- epilogue: combine key-half partials via dead K/V LDS (no shuffles needed) ----
  // lacc[qt][r] = sum_p P[qrow = qt*16 + quad*4 + r][all 32 keys of this half] (all lanes agree)
  __syncthreads();  // all waves done reading Ks/Vs; safe to reuse as reduction scratch
  float* ored = (float*)&Ks[0][0];  // 2qh x 2qt x 4dt x 64lane x f32x4 = 16 KB (= both Ks bufs)
  float* lred = (float*)&Vs[0][0];  // 2qh x 2qt x 16 floats
  if (kh == 1) {
#pragma unroll
    for (int qt = 0; qt < 2; ++qt) {
#pragma unroll
      for (int dt = 0; dt < 4; ++dt)
        *(f32x4*)&ored[((((qh2 * 2 + qt) * 4 + dt) * 64) + lane) * 4] = oacc[qt][dt];
      if (l15 == 0) {
#pragma unroll
        for (int r = 0; r < 4; ++r)
          lred[(qh2 * 2 + qt) * 16 + quad * 4 + r] = lacc[qt][r];
      }
    }
  }
  __syncthreads();
  if (kh == 0) {
#pragma unroll
    for (int qt = 0; qt < 2; ++qt) {
      f32x4 linv;
#pragma unroll
      for (int r = 0; r < 4; ++r)
        linv[r] = 1.f / (lacc[qt][r] + lred[(qh2 * 2 + qt) * 16 + quad * 4 + r]);
#pragma unroll
      for (int dt = 0; dt < 4; ++dt) {
        f32x4 oo = *(const f32x4*)&ored[((((qh2 * 2 + qt) * 4 + dt) * 64) + lane) * 4];
        int row = q0 + qh2 * 32 + qt * 16 + quad * 4;
        u16* op = ob + (size_t)row * 768 + h * 64 + dt * 16 + l15;
        op[0]       = f2bf((oacc[qt][dt][0] + oo[0]) * linv[0]);
        op[768]     = f2bf((oacc[qt][dt][1] + oo[1]) * linv[1]);
        op[2 * 768] = f2bf((oacc[qt][dt][2] + oo[2]) * linv[2]);
        op[3 * 768] = f2bf((oacc[qt][dt][3] + oo[3]) * linv[3]);
      }
    }
  }
}

extern "C" void kernel_launch(void* const* d_in, const int* in_sizes, int n_in,
                              void* d_out, int out_size, void* d_ws, size_t ws_size,
                              hipStream_t stream) {
  const float* x      = (const float*)d_in[0];
  const float* qkv_w  = (const float*)d_in[1];
  const float* qkv_b  = (const float*)d_in[2];
  const float* proj_w = (const float*)d_in[3];
  const float* proj_b = (const float*)d_in[4];
  float* out = (float*)d_out;

  const int N = 4096, C = 768, H = 12, D = 64, C3 = 2304;
  char* ws = (char*)d_ws;
  size_t off = 0;
  u16* xb    = (u16*)(ws + off); off += (size_t)N * C * 2;       // 6.29 MB (reused as attn-out)
  u16* wqkv  = (u16*)(ws + off); off += (size_t)C3 * C * 2;      // 3.54 MB
  u16* wproj = (u16*)(ws + off); off += (size_t)C * C * 2;       // 1.18 MB
  u16* qbuf  = (u16*)(ws + off); off += (size_t)H * N * D * 2;   // 6.29 MB
  u16* kbuf  = (u16*)(ws + off); off += (size_t)H * N * D * 2;
  u16* vbuf  = (u16*)(ws + off); off += (size_t)H * N * D * 2;   // V^T [H][64][4096]
  u16* aob = xb;  // alias: xb dead after QKV GEMM

  const int na4 = N * C / 4, nb4 = C3 * C / 4, nc4 = C * C / 4;
  int ntot = na4 + nb4 + nc4;
  cast3<<<(ntot + 255) / 256, 256, 0, stream>>>(x, na4, qkv_w, nb4, proj_w, nc4, xb, wqkv, wproj);

  dim3 g1(C3 / 128, N / 128);  // 18 x 32
  gemm_bt<0><<<g1, 256, 0, stream>>>(xb, wqkv, qkv_b, qbuf, kbuf, vbuf, nullptr, C, C3);

  flash_attn<<<768, 256, 0, stream>>>(qbuf, kbuf, vbuf, aob);

  dim3 g3(C / 128, N / 64);    // 6 x 64 = 384 blocks (TM=64 retile)
  gemm_bt<1><<<g3, 256, 0, stream>>>(aob, wproj, proj_b, nullptr, nullptr, nullptr, out, C, C);
}